// Round 1
// baseline (270.520 us; speedup 1.0000x reference)
//
#include <hip/hip_runtime.h>

typedef float f32x4 __attribute__((ext_vector_type(4)));
typedef short short8 __attribute__((ext_vector_type(8)));

#define GBL(p) ((__attribute__((address_space(1))) void*)(p))
#define LDS(p) ((__attribute__((address_space(3))) void*)(p))

static __device__ __forceinline__ unsigned short f2bf(float x) {
  union { float f; unsigned u; } a; a.f = x;
  unsigned u = a.u;
  return (unsigned short)((u + 0x7FFFu + ((u >> 16) & 1u)) >> 16);
}

static __device__ __forceinline__ short8 ld8(const unsigned short* p) {
  return *(const short8*)(p);
}

static __device__ __forceinline__ f32x4 zero4() {
  f32x4 z = {0.f, 0.f, 0.f, 0.f};
  return z;
}

// ---------------- fp32 -> bf16 convert ----------------
__global__ void cvt_kernel(const float4* __restrict__ in, ushort4* __restrict__ out, int n4) {
  int i = blockIdx.x * blockDim.x + threadIdx.x;
  if (i >= n4) return;
  float4 v = in[i];
  ushort4 o;
  o.x = f2bf(v.x); o.y = f2bf(v.y); o.z = f2bf(v.z); o.w = f2bf(v.w);
  out[i] = o;
}

// ---------------- GEMM: C[M][N] = A[M][K] * B[N][K]^T (bf16 in, bf16/f32 out) ----------------
template<int OUT_BF16>
__global__ __launch_bounds__(256) void gemm_bt(
    const unsigned short* __restrict__ A,
    const unsigned short* __restrict__ B,
    void* __restrict__ Cout, int M, int N, int K)
{
  __shared__ __align__(16) unsigned short As[128 * 32];
  __shared__ __align__(16) unsigned short Bs[128 * 32];

  const int t = threadIdx.x;
  const int lane = t & 63;
  const int w = t >> 6;
  const int wr = (w >> 1) * 64;     // wave row origin in tile
  const int wc = (w & 1) * 64;      // wave col origin in tile
  const int fr = lane & 15;
  const int kg = lane >> 4;
  const size_t rowBase = (size_t)blockIdx.y * 128;
  const size_t colBase = (size_t)blockIdx.x * 128;

  f32x4 acc[4][4];
  for (int m = 0; m < 4; ++m)
    for (int n = 0; n < 4; ++n) acc[m][n] = zero4();

  // staging: thread t loads 16B at tile row t/4, col (t%3)*8; two 64-row groups
  const unsigned short* ag = A + (rowBase + (t >> 2)) * (size_t)K + (t & 3) * 8;
  const unsigned short* bg = B + (colBase + (t >> 2)) * (size_t)K + (t & 3) * 8;
  unsigned short* asd = As + t * 8;
  unsigned short* bsd = Bs + t * 8;

  for (int k0 = 0; k0 < K; k0 += 32) {
    __builtin_amdgcn_global_load_lds(GBL(ag + k0),                   LDS(asd),        16, 0, 0);
    __builtin_amdgcn_global_load_lds(GBL(ag + (size_t)64 * K + k0),  LDS(asd + 2048), 16, 0, 0);
    __builtin_amdgcn_global_load_lds(GBL(bg + k0),                   LDS(bsd),        16, 0, 0);
    __builtin_amdgcn_global_load_lds(GBL(bg + (size_t)64 * K + k0),  LDS(bsd + 2048), 16, 0, 0);
    __syncthreads();
    short8 af[4], bf[4];
    for (int m = 0; m < 4; ++m) af[m] = ld8(As + (wr + m * 16 + fr) * 32 + kg * 8);
    for (int n = 0; n < 4; ++n) bf[n] = ld8(Bs + (wc + n * 16 + fr) * 32 + kg * 8);
    for (int m = 0; m < 4; ++m)
      for (int n = 0; n < 4; ++n)
        acc[m][n] = __builtin_amdgcn_mfma_f32_16x16x32_bf16(af[m], bf[n], acc[m][n], 0, 0, 0);
    __syncthreads();
  }

  // epilogue: C row = (lane>>4)*4 + reg, col = lane&15 (verified m89/m91 layout)
  for (int m = 0; m < 4; ++m)
    for (int n = 0; n < 4; ++n) {
      const size_t row = rowBase + wr + m * 16 + kg * 4;
      const size_t col = colBase + wc + n * 16 + fr;
      if (OUT_BF16) {
        unsigned short* C = (unsigned short*)Cout;
        for (int j = 0; j < 4; ++j) C[(row + j) * N + col] = f2bf(acc[m][n][j]);
      } else {
        float* C = (float*)Cout;
        for (int j = 0; j < 4; ++j) C[(row + j) * N + col] = acc[m][n][j];
      }
    }
}

// ---------------- causal flash attention ----------------
// qkv: [4096][3072] bf16 (Q cols 0..1023, K cols 1024..2047, V cols 2048..3071)
// om:  [4096][1024] bf16 head-merged attention output
__global__ __launch_bounds__(256) void attn_kernel(
    const unsigned short* __restrict__ qkv,
    unsigned short* __restrict__ om)
{
  __shared__ __align__(16) unsigned short Ps[4][16 * 32];

  const int bh = blockIdx.x;          // b*16 + h
  const int qt = blockIdx.y;          // q-tile (64 rows)
  const int b = bh >> 4, h = bh & 15;
  const int t = threadIdx.x;
  const int lane = t & 63, w = t >> 6;
  const int fr = lane & 15, kg = lane >> 4;
  const int qrow0 = qt * 64 + w * 16; // this wave's 16 q-rows
  const size_t seq0 = (size_t)b * 2048;

  // Q fragments hoisted (row = fr, k = kc*32 + kg*8 + j)
  const unsigned short* qp = qkv + (seq0 + qrow0 + fr) * 3072 + h * 64;
  const short8 qf0 = ld8(qp + kg * 8);
  const short8 qf1 = ld8(qp + 32 + kg * 8);

  float m_run[4], l_run[4];
  f32x4 o[4];
  for (int j = 0; j < 4; ++j) { m_run[j] = -1e30f; l_run[j] = 0.f; }
  for (int n = 0; n < 4; ++n) o[n] = zero4();

  unsigned short* pw = &Ps[w][0];
  const int lastkt = (qrow0 + 15) >> 5;   // causal, wave-uniform

  for (int kt = 0; kt <= lastkt; ++kt) {
    const int kr0 = kt * 32;

    // S = Q K^T : two 16x16 n-tiles, K=64 in 2 mfma steps
    f32x4 s[2];
    for (int n = 0; n < 2; ++n) {
      const unsigned short* kp = qkv + (seq0 + kr0 + n * 16 + fr) * 3072 + 1024 + h * 64;
      short8 kf0 = ld8(kp + kg * 8);
      short8 kf1 = ld8(kp + 32 + kg * 8);
      f32x4 a = zero4();
      a = __builtin_amdgcn_mfma_f32_16x16x32_bf16(qf0, kf0, a, 0, 0, 0);
      a = __builtin_amdgcn_mfma_f32_16x16x32_bf16(qf1, kf1, a, 0, 0, 0);
      s[n] = a;
    }

    // online softmax (rows = kg*4 + j per lane, 16-lane group reduce)
    float p0[4], p1[4];
    for (int j = 0; j < 4; ++j) {
      const int qrow = qrow0 + kg * 4 + j;
      float s0 = s[0][j] * 0.125f;
      float s1 = s[1][j] * 0.125f;
      if (kr0 + fr > qrow)      s0 = -1e30f;
      if (kr0 + 16 + fr > qrow) s1 = -1e30f;
      float mx = fmaxf(s0, s1);
      mx = fmaxf(mx, __shfl_xor(mx, 1));
      mx = fmaxf(mx, __shfl_xor(mx, 2));
      mx = fmaxf(mx, __shfl_xor(mx, 4));
      mx = fmaxf(mx, __shfl_xor(mx, 8));
      const float mn = fmaxf(m_run[j], mx);
      const float al = __expf(m_run[j] - mn);
      const float e0 = __expf(s0 - mn);
      const float e1 = __expf(s1 - mn);
      float sum = e0 + e1;
      sum += __shfl_xor(sum, 1);
      sum += __shfl_xor(sum, 2);
      sum += __shfl_xor(sum, 4);
      sum += __shfl_xor(sum, 8);
      m_run[j] = mn;
      l_run[j] = l_run[j] * al + sum;
      p0[j] = e0; p1[j] = e1;
      o[0][j] *= al; o[1][j] *= al; o[2][j] *= al; o[3][j] *= al;
    }

    // P -> LDS (per-wave, [16 q][32 k] bf16), then read as A-fragment
    for (int j = 0; j < 4; ++j) {
      pw[(kg * 4 + j) * 32 + fr]      = f2bf(p0[j]);
      pw[(kg * 4 + j) * 32 + 16 + fr] = f2bf(p1[j]);
    }
    short8 pf = ld8(pw + fr * 32 + kg * 8);

    // PV: B-fragment of V read direct from global (k = kg*8+j, d = nd*16+fr)
    const unsigned short* vbase = qkv + (seq0 + kr0 + kg * 8) * 3072 + 2048 + h * 64 + fr;
    for (int nd = 0; nd < 4; ++nd) {
      short8 vf;
      const unsigned short* vp = vbase + nd * 16;
      for (int j = 0; j < 8; ++j) vf[j] = (short)vp[(size_t)j * 3072];
      o[nd] = __builtin_amdgcn_mfma_f32_16x16x32_bf16(pf, vf, o[nd], 0, 0, 0);
    }
  }

  // epilogue: normalize and store head-merged bf16
  for (int nd = 0; nd < 4; ++nd)
    for (int j = 0; j < 4; ++j) {
      float v = o[nd][j] / l_run[j];
      om[(seq0 + qrow0 + kg * 4 + j) * 1024 + h * 64 + nd * 16 + fr] = f2bf(v);
    }
}

// ---------------- launch ----------------
extern "C" void kernel_launch(void* const* d_in, const int* in_sizes, int n_in,
                              void* d_out, int out_size, void* d_ws, size_t ws_size,
                              hipStream_t stream) {
  const float* x    = (const float*)d_in[0];   // [2,2048,1024]
  const float* Wqkv = (const float*)d_in[1];   // [3072,1024]
  const float* Wout = (const float*)d_in[2];   // [1024,1024]
  float* out = (float*)d_out;                  // [2,2048,1024]

  char* ws = (char*)d_ws;
  unsigned short* xb    = (unsigned short*)(ws);                      //  8 MB  [4096][1024]
  unsigned short* wqkvb = (unsigned short*)(ws + 8388608);            //  6 MB  [3072][1024]
  unsigned short* woutb = (unsigned short*)(ws + 14680064);           //  2 MB  [1024][1024]
  unsigned short* qkvb  = (unsigned short*)(ws + 16777216);           // 24 MB  [4096][3072]
  unsigned short* attno = (unsigned short*)(ws + 41943040);           //  8 MB  [4096][1024]

  cvt_kernel<<<dim3(4096), dim3(256), 0, stream>>>((const float4*)x,    (ushort4*)xb,    1048576);
  cvt_kernel<<<dim3(3072), dim3(256), 0, stream>>>((const float4*)Wqkv, (ushort4*)wqkvb, 786432);
  cvt_kernel<<<dim3(1024), dim3(256), 0, stream>>>((const float4*)Wout, (ushort4*)woutb, 262144);

  gemm_bt<1><<<dim3(24, 32), dim3(256), 0, stream>>>(xb, wqkvb, (void*)qkvb, 4096, 3072, 1024);

  attn_kernel<<<dim3(32, 32), dim3(256), 0, stream>>>(qkvb, attno);

  gemm_bt<0><<<dim3(8, 32), dim3(256), 0, stream>>>(attno, woutb, (void*)out, 4096, 1024, 1024);
}